// Round 4
// baseline (174.204 us; speedup 1.0000x reference)
//
#include <hip/hip_runtime.h>

#define BB 16
#define CC 80
#define DD 1024
#define HW 196
#define NSP (BB * HW)        // 3136 = 49 full waves, zero lane waste
#define NCH 8                // d-chunks of 128
#define DCH 128
#define CPB 4                // classes per scores block (R3's CPB=8 regressed)
#define NCQ (CC / CPB)       // 20 class-groups -> grid 2080 blocks
#define TWO_LOG2E 2.8853900817779268f

// imgT rows are d-rotated by 64*(row&15) floats to break the exact-4KB
// h-stride that set-thrashes L1/L2 in the pool kernel. Rotation is a
// multiple of 64, so scores' 32-aligned 32-float store chunks never wrap.
#define ROT(row) ((((row) & 15)) << 6)

// ---------------- K1: scores (R0-proven structure) + rotated imgT ------------
__global__ __launch_bounds__(256) void scores_k(const float* __restrict__ img,
                                                const float* __restrict__ word,
                                                const float* __restrict__ fa,
                                                float* __restrict__ partial,
                                                float* __restrict__ imgT) {
    const int g = blockIdx.x * 256 + threadIdx.x;
    if (g >= NSP) return;                           // wave-uniform exit
    const int b  = g / HW;
    const int hw = g - b * HW;
    const int d0 = blockIdx.y * DCH;
    const int c0 = blockIdx.z * CPB;

    const float* ip = img + ((size_t)b * DD + d0) * HW + hw;

    float p[CPB];
#pragma unroll
    for (int k = 0; k < CPB; ++k) p[k] = 0.f;

    for (int q = 0; q < DCH / 32; ++q) {            // 4 quarters of 32 d
        float iv[32];
        const float* qp = ip + (size_t)q * 32 * HW;
#pragma unroll
        for (int i = 0; i < 32; ++i)
            iv[i] = qp[(size_t)i * HW];

        if (blockIdx.z == 0) {                       // block-uniform branch
            const int base = (d0 + q * 32 + ROT(g)) & (DD - 1);  // 32-aligned
            float4* tp = (float4*)(imgT + (size_t)g * DD + base);
#pragma unroll
            for (int i = 0; i < 8; ++i)
                tp[i] = make_float4(iv[4 * i], iv[4 * i + 1], iv[4 * i + 2], iv[4 * i + 3]);
        }

#pragma unroll
        for (int i = 0; i < 32; ++i)
            iv[i] *= TWO_LOG2E;                      // exp2(iv*w) == e^{2x}

        const float* fp = fa + d0 + q * 32;          // uniform -> SGPRs
#pragma unroll
        for (int k = 0; k < CPB; ++k) {
            const float* wp = word + (size_t)(c0 + k) * DD + d0 + q * 32;
            float p0 = 0.f, p1 = 0.f;
#pragma unroll
            for (int i = 0; i < 32; i += 2) {
                float y0 = iv[i]     * wp[i];
                float y1 = iv[i + 1] * wp[i + 1];
                float e0 = __builtin_amdgcn_exp2f(y0);
                float e1 = __builtin_amdgcn_exp2f(y1);
                float r0 = __builtin_amdgcn_rcpf(e0 + 1.f);
                float r1 = __builtin_amdgcn_rcpf(e1 + 1.f);
                p0 = fmaf(fp[i],     r0, p0);
                p1 = fmaf(fp[i + 1], r1, p1);
            }
            p[k] += p0 + p1;
        }
    }

#pragma unroll
    for (int k = 0; k < CPB; ++k)
        partial[(((size_t)b * NCH + blockIdx.y) * CC + (c0 + k)) * HW + hw]
            = (-TWO_LOG2E) * p[k];
}

// ---------------- K2: fused softmax + pooling (R0 structure, rotated reads) --
// Grid (16 b, 4 d-tiles of 256, 20 c-groups of 4) = 1280 blocks x 4 waves
// = 20 waves/CU. Phase S unchanged (bitwise-identical softmax). Phase P:
// identical instruction mix to R0 (4 global b32 + 4 broadcast ds_read_b128
// + 16 v_fma per 4-h step); only the imgT index adds the per-row rotation.
__global__ __launch_bounds__(256) void pool2_k(const float* __restrict__ imgT,
                                               const float* __restrict__ partial,
                                               float* __restrict__ out) {
    __shared__ float ct[4 * HW];                  // 3136 B
    const int b   = blockIdx.x;
    const int dt0 = blockIdx.y * 256;
    const int cg  = blockIdx.z * 4;
    const int t   = threadIdx.x;
    const int w   = t >> 6, l = t & 63;

    // ---- Phase S: wave w -> softmax of class cg+w ----
    {
        const int c = cg + w;
        float x0 = 0.f, x1 = 0.f, x2 = 0.f, x3 = 0.f;
#pragma unroll
        for (int ch = 0; ch < NCH; ++ch) {
            const float* pp = partial + (((size_t)b * NCH + ch) * CC + c) * HW;
            x0 += pp[l];
            x1 += pp[l + 64];
            x2 += pp[l + 128];
            if (l < HW - 192) x3 += pp[l + 192];
        }
        float x3m = (l < HW - 192) ? x3 : -3.4e38f;

        float m = fmaxf(fmaxf(x0, x1), fmaxf(x2, x3m));
#pragma unroll
        for (int off = 32; off >= 1; off >>= 1) m = fmaxf(m, __shfl_xor(m, off, 64));

        float e0 = __builtin_amdgcn_exp2f(x0 - m);
        float e1 = __builtin_amdgcn_exp2f(x1 - m);
        float e2 = __builtin_amdgcn_exp2f(x2 - m);
        float e3 = (l < HW - 192) ? __builtin_amdgcn_exp2f(x3 - m) : 0.f;

        float s = (e0 + e1) + (e2 + e3);
#pragma unroll
        for (int off = 32; off >= 1; off >>= 1) s += __shfl_xor(s, off, 64);

        float inv = __builtin_amdgcn_rcpf(s);
        float* cr = ct + w * HW;
        cr[l]       = e0 * inv;
        cr[l + 64]  = e1 * inv;
        cr[l + 128] = e2 * inv;
        if (l < HW - 192) cr[l + 192] = e3 * inv;
    }
    __syncthreads();

    // ---- Phase P: thread owns d = dt0 + t (reads de-rotated) ----
    const float* rb = imgT + (size_t)b * HW * DD;   // batch base, row stride DD
    const int du = dt0 + t;
    const int rbase = 4 * b;                         // (b*196) & 15 == (4b) & 15

    float a0 = 0.f, a1 = 0.f, a2 = 0.f, a3 = 0.f;
#pragma unroll 7
    for (int h = 0; h < HW; h += 4) {
        const int r0 = ((rbase + h    ) & 15) << 6;
        const int r1 = ((rbase + h + 1) & 15) << 6;
        const int r2 = ((rbase + h + 2) & 15) << 6;
        const int r3 = ((rbase + h + 3) & 15) << 6;
        float i0 = rb[(size_t)(h    ) * DD + ((du + r0) & (DD - 1))];
        float i1 = rb[(size_t)(h + 1) * DD + ((du + r1) & (DD - 1))];
        float i2 = rb[(size_t)(h + 2) * DD + ((du + r2) & (DD - 1))];
        float i3 = rb[(size_t)(h + 3) * DD + ((du + r3) & (DD - 1))];
        float4 c0v = *(const float4*)(ct + h);            // broadcast b128
        float4 c1v = *(const float4*)(ct + HW + h);
        float4 c2v = *(const float4*)(ct + 2 * HW + h);
        float4 c3v = *(const float4*)(ct + 3 * HW + h);
        a0 = fmaf(c0v.x, i0, fmaf(c0v.y, i1, fmaf(c0v.z, i2, fmaf(c0v.w, i3, a0))));
        a1 = fmaf(c1v.x, i0, fmaf(c1v.y, i1, fmaf(c1v.z, i2, fmaf(c1v.w, i3, a1))));
        a2 = fmaf(c2v.x, i0, fmaf(c2v.y, i1, fmaf(c2v.z, i2, fmaf(c2v.w, i3, a2))));
        a3 = fmaf(c3v.x, i0, fmaf(c3v.y, i1, fmaf(c3v.z, i2, fmaf(c3v.w, i3, a3))));
    }

    float* ob = out + ((size_t)b * CC + cg) * DD + dt0 + t;
    ob[0]              = a0;
    ob[DD]             = a1;
    ob[2 * (size_t)DD] = a2;
    ob[3 * (size_t)DD] = a3;
}

extern "C" void kernel_launch(void* const* d_in, const int* in_sizes, int n_in,
                              void* d_out, int out_size, void* d_ws, size_t ws_size,
                              hipStream_t stream) {
    // inputs: [0]=batch_size(int,1) [1]=img [2]=word [3]=fc_a_w [4]=fc_a_b
    const float* img  = (const float*)d_in[1];
    const float* word = (const float*)d_in[2];
    const float* fa   = (const float*)d_in[3];
    float* out = (float*)d_out;

    // workspace (floats): partial[16][8][80][196] = 8.03 MB
    //                   | imgT[3136][1024]        = 12.85 MB  (20.88 MB, proven)
    float* partial = (float*)d_ws;
    float* imgT    = partial + (size_t)BB * NCH * CC * HW;

    scores_k<<<dim3((NSP + 255) / 256, NCH, NCQ), 256, 0, stream>>>(img, word, fa, partial, imgT);
    pool2_k<<<dim3(BB, DD / 256, CC / 4), 256, 0, stream>>>(imgT, partial, out);
}

// Round 5
// 150.282 us; speedup vs baseline: 1.1592x; 1.1592x over previous
//
#include <hip/hip_runtime.h>

#define BB 16
#define CC 80
#define DD 1024
#define HW 196
#define NSP (BB * HW)        // 3136 = 49 full waves, zero lane waste
#define NCH 8                // d-chunks of 128
#define DCH 128
#define CPB 4                // classes per scores block
#define NCQ (CC / CPB)       // 20 class-groups -> grid 2080 blocks
#define TWO_LOG2E 2.8853900817779268f

// ---------------- K1: scores (R0-proven, bitwise-identical) + imgT -----------
__global__ __launch_bounds__(256) void scores_k(const float* __restrict__ img,
                                                const float* __restrict__ word,
                                                const float* __restrict__ fa,
                                                float* __restrict__ partial,
                                                float* __restrict__ imgT) {
    const int g = blockIdx.x * 256 + threadIdx.x;
    if (g >= NSP) return;                           // wave-uniform exit
    const int b  = g / HW;
    const int hw = g - b * HW;
    const int d0 = blockIdx.y * DCH;
    const int c0 = blockIdx.z * CPB;

    const float* ip = img + ((size_t)b * DD + d0) * HW + hw;

    float p[CPB];
#pragma unroll
    for (int k = 0; k < CPB; ++k) p[k] = 0.f;

    for (int q = 0; q < DCH / 32; ++q) {            // 4 quarters of 32 d
        float iv[32];
        const float* qp = ip + (size_t)q * 32 * HW;
#pragma unroll
        for (int i = 0; i < 32; ++i)
            iv[i] = qp[(size_t)i * HW];

        if (blockIdx.z == 0) {                       // block-uniform branch
            float4* tp = (float4*)(imgT + (size_t)g * DD + d0 + q * 32);
#pragma unroll
            for (int i = 0; i < 8; ++i)
                tp[i] = make_float4(iv[4 * i], iv[4 * i + 1], iv[4 * i + 2], iv[4 * i + 3]);
        }

#pragma unroll
        for (int i = 0; i < 32; ++i)
            iv[i] *= TWO_LOG2E;                      // exp2(iv*w) == e^{2x}

        const float* fp = fa + d0 + q * 32;          // uniform -> SGPRs
#pragma unroll
        for (int k = 0; k < CPB; ++k) {
            const float* wp = word + (size_t)(c0 + k) * DD + d0 + q * 32;
            float p0 = 0.f, p1 = 0.f;
#pragma unroll
            for (int i = 0; i < 32; i += 2) {
                float y0 = iv[i]     * wp[i];
                float y1 = iv[i + 1] * wp[i + 1];
                float e0 = __builtin_amdgcn_exp2f(y0);
                float e1 = __builtin_amdgcn_exp2f(y1);
                float r0 = __builtin_amdgcn_rcpf(e0 + 1.f);
                float r1 = __builtin_amdgcn_rcpf(e1 + 1.f);
                p0 = fmaf(fp[i],     r0, p0);
                p1 = fmaf(fp[i + 1], r1, p1);
            }
            p[k] += p0 + p1;
        }
    }

#pragma unroll
    for (int k = 0; k < CPB; ++k)
        partial[(((size_t)b * NCH + blockIdx.y) * CC + (c0 + k)) * HW + hw]
            = (-TWO_LOG2E) * p[k];
}

// ---------------- K2: fused softmax + pooling (R0 structure + XCD swizzle) ---
// Grid 1280 blocks x 4 waves = 20 waves/CU, identical instruction mix to R0.
// ONE change: block->(b,dt,cg) is remapped so that, assuming the dispatcher
// round-robins linear block id across the 8 XCDs (id%8=XCD), each XCD owns
// exactly 2 batches. All 80 blocks re-reading a given b's imgT (800 KB) and
// partial (627 KB) then share ONE private 4 MiB L2: 19 of the 20 class-group
// re-reads become local L2 hits instead of L3/IF round-trips.
__global__ __launch_bounds__(256) void pool2_k(const float* __restrict__ imgT,
                                               const float* __restrict__ partial,
                                               float* __restrict__ out) {
    __shared__ float ct[4 * HW];                  // 3136 B
    // linear id, blockIdx.x fastest; bijective remap onto (b, dt, cg)
    const int n = blockIdx.x + BB * (blockIdx.y + 4 * blockIdx.z);
    const int X = n & 7;                          // XCD (assumed id%8)
    const int s = n >> 3;                         // slot within XCD, 0..159
    const int b   = X + 8 * (s & 1);              // 2 batches per XCD
    const int r   = s >> 1;                       // 0..79
    const int dt0 = (r / 20) * 256;               // 4 d-tiles
    const int cg  = (r % 20) * 4;                 // 20 class-groups
    const int t   = threadIdx.x;
    const int w   = t >> 6, l = t & 63;

    // ---- Phase S: wave w -> softmax of class cg+w ----
    {
        const int c = cg + w;
        float x0 = 0.f, x1 = 0.f, x2 = 0.f, x3 = 0.f;
#pragma unroll
        for (int ch = 0; ch < NCH; ++ch) {
            const float* pp = partial + (((size_t)b * NCH + ch) * CC + c) * HW;
            x0 += pp[l];
            x1 += pp[l + 64];
            x2 += pp[l + 128];
            if (l < HW - 192) x3 += pp[l + 192];
        }
        float x3m = (l < HW - 192) ? x3 : -3.4e38f;

        float m = fmaxf(fmaxf(x0, x1), fmaxf(x2, x3m));
#pragma unroll
        for (int off = 32; off >= 1; off >>= 1) m = fmaxf(m, __shfl_xor(m, off, 64));

        float e0 = __builtin_amdgcn_exp2f(x0 - m);
        float e1 = __builtin_amdgcn_exp2f(x1 - m);
        float e2 = __builtin_amdgcn_exp2f(x2 - m);
        float e3 = (l < HW - 192) ? __builtin_amdgcn_exp2f(x3 - m) : 0.f;

        float s2 = (e0 + e1) + (e2 + e3);
#pragma unroll
        for (int off = 32; off >= 1; off >>= 1) s2 += __shfl_xor(s2, off, 64);

        float inv = __builtin_amdgcn_rcpf(s2);
        float* cr = ct + w * HW;
        cr[l]       = e0 * inv;
        cr[l + 64]  = e1 * inv;
        cr[l + 128] = e2 * inv;
        if (l < HW - 192) cr[l + 192] = e3 * inv;
    }
    __syncthreads();

    // ---- Phase P: thread owns d = dt0 + t ----
    const float* ib = imgT + (size_t)b * HW * DD + dt0 + t;

    float a0 = 0.f, a1 = 0.f, a2 = 0.f, a3 = 0.f;
#pragma unroll 7
    for (int h = 0; h < HW; h += 4) {
        float i0 = ib[(size_t)(h    ) * DD];
        float i1 = ib[(size_t)(h + 1) * DD];
        float i2 = ib[(size_t)(h + 2) * DD];
        float i3 = ib[(size_t)(h + 3) * DD];
        float4 c0v = *(const float4*)(ct + h);            // broadcast b128
        float4 c1v = *(const float4*)(ct + HW + h);
        float4 c2v = *(const float4*)(ct + 2 * HW + h);
        float4 c3v = *(const float4*)(ct + 3 * HW + h);
        a0 = fmaf(c0v.x, i0, fmaf(c0v.y, i1, fmaf(c0v.z, i2, fmaf(c0v.w, i3, a0))));
        a1 = fmaf(c1v.x, i0, fmaf(c1v.y, i1, fmaf(c1v.z, i2, fmaf(c1v.w, i3, a1))));
        a2 = fmaf(c2v.x, i0, fmaf(c2v.y, i1, fmaf(c2v.z, i2, fmaf(c2v.w, i3, a2))));
        a3 = fmaf(c3v.x, i0, fmaf(c3v.y, i1, fmaf(c3v.z, i2, fmaf(c3v.w, i3, a3))));
    }

    float* ob = out + ((size_t)b * CC + cg) * DD + dt0 + t;
    ob[0]              = a0;
    ob[DD]             = a1;
    ob[2 * (size_t)DD] = a2;
    ob[3 * (size_t)DD] = a3;
}

extern "C" void kernel_launch(void* const* d_in, const int* in_sizes, int n_in,
                              void* d_out, int out_size, void* d_ws, size_t ws_size,
                              hipStream_t stream) {
    // inputs: [0]=batch_size(int,1) [1]=img [2]=word [3]=fc_a_w [4]=fc_a_b
    const float* img  = (const float*)d_in[1];
    const float* word = (const float*)d_in[2];
    const float* fa   = (const float*)d_in[3];
    float* out = (float*)d_out;

    // workspace (floats): partial[16][8][80][196] = 8.03 MB
    //                   | imgT[3136][1024]        = 12.85 MB  (20.88 MB, proven)
    float* partial = (float*)d_ws;
    float* imgT    = partial + (size_t)BB * NCH * CC * HW;

    scores_k<<<dim3((NSP + 255) / 256, NCH, NCQ), 256, 0, stream>>>(img, word, fa, partial, imgT);
    pool2_k<<<dim3(BB, DD / 256, CC / 4), 256, 0, stream>>>(imgT, partial, out);
}